// Round 4
// baseline (483.752 us; speedup 1.0000x reference)
//
#include <hip/hip_runtime.h>

// LightGCN propagation on MI355X — CSR-gather, separable-norm formulation.
// N = 150000 nodes, D = 64, E = 1.2M edges, 4 layers.
// norm = dinv[src]*dinv[dst] is factored: keep z = dinv .* emb, so the
// per-edge gather is an UNWEIGHTED row sum; epilogue applies dinv[dst].
// d_out (= acc) accumulates sum of layer embeddings pre-scaled by 1/25.

#define DIMH 64
#define BLK 256
#define SCAN_ITEMS 8
#define SCAN_CHUNK (BLK * SCAN_ITEMS)  // 2048 elements per scan block

typedef float f32x4 __attribute__((ext_vector_type(4)));

__device__ inline void nt_store4(float* p, float x, float y, float z, float w) {
    f32x4 v = {x, y, z, w};
    __builtin_nontemporal_store(v, (f32x4*)p);
}

// ---------------------------------------------------------------------------
// init: embA = concat(user, item); acc = embA/25; cnt = 0 (fused memset).
__global__ void k_init(const float* __restrict__ uemb, const float* __restrict__ iemb,
                       float* __restrict__ embA, float* __restrict__ acc,
                       int* __restrict__ cnt, long uElems, long totalElems, long N) {
    long t = (long)blockIdx.x * BLK + threadIdx.x;
    if (t < N) cnt[t] = 0;
    long base = t * 4;
    if (base >= totalElems) return;
    float4 v = (base < uElems) ? *(const float4*)(uemb + base)
                               : *(const float4*)(iemb + (base - uElems));
    *(float4*)(embA + base) = v;
    const float s = 1.0f / 25.0f;
    nt_store4(acc + base, v.x * s, v.y * s, v.z * s, v.w * s);
}

// dst-degree histogram (int atomics).
__global__ void k_deg(const int* __restrict__ col, int* __restrict__ cnt, long E) {
    long e = (long)blockIdx.x * BLK + threadIdx.x;
    if (e < E) atomicAdd(&cnt[col[e]], 1);
}

// --- hierarchical exclusive scan of cnt[N] -> rowptr[N+1] ------------------
// pass 1: per-block sums; fused: dinv[n] = cnt[n]>0 ? rsqrt(cnt[n]) : 0
__global__ void k_scan_partial(const int* __restrict__ cnt, float* __restrict__ dinv,
                               int* __restrict__ bsum, long N) {
    __shared__ int lds[BLK];
    long base = (long)blockIdx.x * SCAN_CHUNK + (long)threadIdx.x * SCAN_ITEMS;
    int tsum = 0;
    for (int i = 0; i < SCAN_ITEMS; ++i) {
        long idx = base + i;
        int c = (idx < N) ? cnt[idx] : 0;
        if (idx < N) dinv[idx] = (c > 0) ? rsqrtf((float)c) : 0.0f;
        tsum += c;
    }
    lds[threadIdx.x] = tsum;
    __syncthreads();
    for (int off = BLK / 2; off > 0; off >>= 1) {
        if (threadIdx.x < off) lds[threadIdx.x] += lds[threadIdx.x + off];
        __syncthreads();
    }
    if (threadIdx.x == 0) bsum[blockIdx.x] = lds[0];
}

// pass 2: single-block exclusive scan of block sums (nb <= 128); also writes
// rowptr[N] = E.
__global__ void k_scan_bsums(const int* __restrict__ bsum, int* __restrict__ boff,
                             int nb, int* __restrict__ rowptrN, int E) {
    __shared__ int lds[128];
    int t = threadIdx.x;
    int v = (t < nb) ? bsum[t] : 0;
    lds[t] = v;
    __syncthreads();
    for (int off = 1; off < 128; off <<= 1) {
        int mine = lds[t];
        int add = (t >= off) ? lds[t - off] : 0;
        __syncthreads();
        lds[t] = mine + add;
        __syncthreads();
    }
    int excl = (t > 0) ? lds[t - 1] : 0;
    if (t < nb) boff[t] = excl;
    if (t == 0) *rowptrN = E;
}

// pass 3: per-element exclusive scan + block offset
__global__ void k_scan_write(const int* __restrict__ cnt, const int* __restrict__ boff,
                             int* __restrict__ rowptr, long N) {
    __shared__ int lds[BLK];
    long base = (long)blockIdx.x * SCAN_CHUNK + (long)threadIdx.x * SCAN_ITEMS;
    int v[SCAN_ITEMS];
    int tsum = 0;
    for (int i = 0; i < SCAN_ITEMS; ++i) {
        long idx = base + i;
        v[i] = (idx < N) ? cnt[idx] : 0;
        tsum += v[i];
    }
    lds[threadIdx.x] = tsum;
    __syncthreads();
    for (int off = 1; off < BLK; off <<= 1) {
        int mine = lds[threadIdx.x];
        int add = (threadIdx.x >= off) ? lds[threadIdx.x - off] : 0;
        __syncthreads();
        lds[threadIdx.x] = mine + add;
        __syncthreads();
    }
    int run = boff[blockIdx.x] + ((threadIdx.x > 0) ? lds[threadIdx.x - 1] : 0);
    for (int i = 0; i < SCAN_ITEMS; ++i) {
        long idx = base + i;
        if (idx < N) rowptr[idx] = run;
        run += v[i];
    }
}

// z = dinv[node] .* emb, in place. Prepares layer-0 scaled embeddings.
__global__ void k_scale(float* __restrict__ emb, const float* __restrict__ dinv,
                        long totalElems) {
    long base = ((long)blockIdx.x * BLK + threadIdx.x) * 4;
    if (base >= totalElems) return;
    float d = dinv[base >> 6];  // node index; broadcast within each 16-thread group
    float4 v = *(float4*)(emb + base);
    v.x *= d; v.y *= d; v.z *= d; v.w *= d;
    *(float4*)(emb + base) = v;
}

// fill CSR: edges[pos] = src only (norm is factored out). Consumes cnt.
__global__ void k_fill(const int* __restrict__ row, const int* __restrict__ col,
                       const int* __restrict__ rowptr,
                       int* __restrict__ cnt, int* __restrict__ edges, long E) {
    long e = (long)blockIdx.x * BLK + threadIdx.x;
    if (e >= E) return;
    int r = __builtin_nontemporal_load(row + e);
    int c = __builtin_nontemporal_load(col + e);
    int k = atomicSub(&cnt[c], 1) - 1;
    __builtin_nontemporal_store(r, edges + rowptr[c] + k);
}

// gather: 16 lanes per dst node; each lane owns a float4 slice of the 64-dim
// row. s = sum over in-edges of z[src]; then
//   emb_next = dinv[dst]*s;  acc += emb_next/25;  z_next = dinv[dst]*emb_next.
// Grid-stride over N*16 virtual threads; inner edge loop unrolled x4 for MLP.
__global__ void __launch_bounds__(BLK)
k_gather(const float* __restrict__ cur, float* __restrict__ nxt,
         float* __restrict__ acc, const float* __restrict__ dinv,
         const int* __restrict__ rowptr, const int* __restrict__ edges,
         long N, int storeNxt) {
    const long gtotal = N * 16;
    const long gstride = (long)gridDim.x * BLK;
    for (long g = (long)blockIdx.x * BLK + threadIdx.x; g < gtotal; g += gstride) {
        long node = g >> 4;
        int q = (int)(g & 15);

        int beg = rowptr[node];
        int end = rowptr[node + 1];

        float sx = 0.f, sy = 0.f, sz = 0.f, sw = 0.f;
        float tx = 0.f, ty = 0.f, tz = 0.f, tw = 0.f;
        for (int base = beg; base < end; base += 16) {
            int me = base + q;
            int psrc = (me < end) ? __builtin_nontemporal_load(edges + me) : 0;
            int n = end - base;
            if (n > 16) n = 16;
            int j = 0;
            for (; j + 4 <= n; j += 4) {
                int a0 = __shfl(psrc, j + 0, 16);
                int a1 = __shfl(psrc, j + 1, 16);
                int a2 = __shfl(psrc, j + 2, 16);
                int a3 = __shfl(psrc, j + 3, 16);
                float4 v0 = *(const float4*)(cur + (long)a0 * DIMH + q * 4);
                float4 v1 = *(const float4*)(cur + (long)a1 * DIMH + q * 4);
                float4 v2 = *(const float4*)(cur + (long)a2 * DIMH + q * 4);
                float4 v3 = *(const float4*)(cur + (long)a3 * DIMH + q * 4);
                sx += v0.x; sy += v0.y; sz += v0.z; sw += v0.w;
                tx += v1.x; ty += v1.y; tz += v1.z; tw += v1.w;
                sx += v2.x; sy += v2.y; sz += v2.z; sw += v2.w;
                tx += v3.x; ty += v3.y; tz += v3.z; tw += v3.w;
            }
            for (; j < n; ++j) {
                int a = __shfl(psrc, j, 16);
                float4 v = *(const float4*)(cur + (long)a * DIMH + q * 4);
                sx += v.x; sy += v.y; sz += v.z; sw += v.w;
            }
        }
        sx += tx; sy += ty; sz += tz; sw += tw;

        float d = dinv[node];
        float ex = d * sx, ey = d * sy, ez = d * sz, ew = d * sw;

        long off = node * DIMH + q * 4;
        const float sc = 1.0f / 25.0f;
        float4 a = *(const float4*)(acc + off);
        nt_store4(acc + off, a.x + ex * sc, a.y + ey * sc, a.z + ez * sc, a.w + ew * sc);
        if (storeNxt) nt_store4(nxt + off, d * ex, d * ey, d * ez, d * ew);
    }
}

// ---------------------------------------------------------------------------
extern "C" void kernel_launch(void* const* d_in, const int* in_sizes, int n_in,
                              void* d_out, int out_size, void* d_ws, size_t ws_size,
                              hipStream_t stream) {
    const float* uemb = (const float*)d_in[0];
    const float* iemb = (const float*)d_in[1];
    const int*   edge = (const int*)d_in[2];

    const long uElems = in_sizes[0];          // 100000*64
    const long iElems = in_sizes[1];          // 50000*64
    const long E      = in_sizes[2] / 2;      // 1200000
    const long total  = uElems + iElems;      // N*64
    const long N      = total / DIMH;         // 150000

    const int* row = edge;      // edge_index[0] = src
    const int* col = edge + E;  // edge_index[1] = dst

    float* acc = (float*)d_out;

    // workspace layout (keep every base 16B-aligned: pads are multiples of 64)
    const long Npad = (N + 63) & ~63L;
    const long Epad = (E + 63) & ~63L;
    int*   cnt    = (int*)d_ws;               // N ints (consumed by k_fill)
    int*   rowptr = cnt + Npad;               // N+1 ints
    int*   bsum   = rowptr + Npad + 64;       // <=128 ints
    int*   boff   = bsum + 128;               // <=128 ints
    float* dinv   = (float*)(boff + 128);     // N floats
    int*   edges  = (int*)(dinv + Npad);      // E src indices (CSR order)
    float* embA   = (float*)(edges + Epad);   // N*64 floats (z ping)
    float* embB   = embA + total;             // N*64 floats (z pong)

    const int nb = (int)((N + SCAN_CHUNK - 1) / SCAN_CHUNK);  // 74 blocks

    const long total4 = total / 4;
    const int gInit = (int)((total4 + BLK - 1) / BLK);
    k_init<<<gInit, BLK, 0, stream>>>(uemb, iemb, embA, acc, cnt, uElems, total, N);
    k_deg<<<(E + BLK - 1) / BLK, BLK, 0, stream>>>(col, cnt, E);
    k_scan_partial<<<nb, BLK, 0, stream>>>(cnt, dinv, bsum, N);
    k_scan_bsums<<<1, 128, 0, stream>>>(bsum, boff, nb, rowptr + N, (int)E);
    k_scan_write<<<nb, BLK, 0, stream>>>(cnt, boff, rowptr, N);
    k_fill<<<(E + BLK - 1) / BLK, BLK, 0, stream>>>(row, col, rowptr, cnt, edges, E);
    k_scale<<<gInit, BLK, 0, stream>>>(embA, dinv, total);

    float* cur = embA;
    float* nxt = embB;
    for (int l = 0; l < 4; ++l) {
        k_gather<<<2048, BLK, 0, stream>>>(cur, nxt, acc, dinv, rowptr, edges, N,
                                           (l < 3) ? 1 : 0);
        float* t = cur; cur = nxt; nxt = t;
    }
}

// Round 6
// 403.753 us; speedup vs baseline: 1.1981x; 1.1981x over previous
//
#include <hip/hip_runtime.h>

// LightGCN propagation on MI355X — CSR-gather, separable-norm, binned CSR build.
// N = 150000 nodes, D = 64, E = 1.2M edges, 4 layers.
// norm = dinv[src]*dinv[dst] is factored: keep z = dinv .* emb, so the
// per-edge gather is an UNWEIGHTED row sum; epilogue applies dinv[dst].
// CSR build: bucket edges by dst>>9 (locality-friendly two-pass scatter),
// then one block per bucket counts/scans/places — all writes CU-local.
// d_out (= acc) accumulates sum of layer embeddings pre-scaled by 1/25.

#define DIMH 64
#define BLK 256
#define BSHIFT 9                    // 512 nodes per bucket
#define BNODES 512
#define EB 8192                     // edges per binscatter block

// ---------------------------------------------------------------------------
// init: embA = concat(user, item); acc = embA/25; bucketCnt = 0 (fused).
__global__ void k_init(const float* __restrict__ uemb, const float* __restrict__ iemb,
                       float* __restrict__ embA, float* __restrict__ acc,
                       int* __restrict__ bucketCnt, long uElems, long totalElems) {
    long t = (long)blockIdx.x * BLK + threadIdx.x;
    if (t < 1024) bucketCnt[t] = 0;
    long base = t * 4;
    if (base >= totalElems) return;
    float4 v = (base < uElems) ? *(const float4*)(uemb + base)
                               : *(const float4*)(iemb + (base - uElems));
    *(float4*)(embA + base) = v;
    const float s = 1.0f / 25.0f;
    *(float4*)(acc + base) = make_float4(v.x * s, v.y * s, v.z * s, v.w * s);
}

// bucket histogram over dst (LDS pre-aggregation, few global atomics).
__global__ void k_binhist(const int* __restrict__ col, int* __restrict__ bucketCnt,
                          long E) {
    __shared__ int h[BNODES];
    for (int i = threadIdx.x; i < BNODES; i += BLK) h[i] = 0;
    __syncthreads();
    const long stride = (long)gridDim.x * BLK;
    for (long e = (long)blockIdx.x * BLK + threadIdx.x; e < E; e += stride)
        atomicAdd(&h[col[e] >> BSHIFT], 1);
    __syncthreads();
    for (int i = threadIdx.x; i < BNODES; i += BLK)
        if (h[i]) atomicAdd(&bucketCnt[i], h[i]);
}

// single-block exclusive scan of bucketCnt[NB] -> bucketPtr, bucketCur.
// Also bucketPtr[NB] = E, rowptr[N] = E.
__global__ void k_binscan(const int* __restrict__ bucketCnt, int* __restrict__ bucketPtr,
                          int* __restrict__ bucketCur, int NB, int E,
                          int* __restrict__ rowptrN) {
    __shared__ int lds[BLK];
    int t = threadIdx.x;
    int v0 = (2 * t < NB) ? bucketCnt[2 * t] : 0;
    int v1 = (2 * t + 1 < NB) ? bucketCnt[2 * t + 1] : 0;
    lds[t] = v0 + v1;
    __syncthreads();
    for (int off = 1; off < BLK; off <<= 1) {
        int mine = lds[t];
        int add = (t >= off) ? lds[t - off] : 0;
        __syncthreads();
        lds[t] = mine + add;
        __syncthreads();
    }
    int excl = (t > 0) ? lds[t - 1] : 0;
    if (2 * t < NB)     { bucketPtr[2 * t] = excl;          bucketCur[2 * t] = excl; }
    if (2 * t + 1 < NB) { bucketPtr[2 * t + 1] = excl + v0; bucketCur[2 * t + 1] = excl + v0; }
    if (t == 0) { bucketPtr[NB] = E; *rowptrN = E; }
}

// scatter (src,dst) pairs into bucket-grouped staging. Per-block LDS
// histogram -> one global reservation per (block,bucket) -> writes to each
// bucket are a contiguous ~16-edge run from a single CU (line-local).
__global__ void k_binscatter(const int* __restrict__ row, const int* __restrict__ col,
                             int* __restrict__ bucketCur, int2* __restrict__ staging,
                             long E) {
    __shared__ int h[BNODES];
    __shared__ int gb[BNODES];
    __shared__ int lc[BNODES];
    const long e0 = (long)blockIdx.x * EB;
    const int n = (int)((E - e0 < EB) ? (E - e0) : EB);
    for (int i = threadIdx.x; i < BNODES; i += BLK) h[i] = 0;
    __syncthreads();
    for (int i = threadIdx.x; i < n; i += BLK)
        atomicAdd(&h[col[e0 + i] >> BSHIFT], 1);
    __syncthreads();
    for (int b = threadIdx.x; b < BNODES; b += BLK) {
        int c = h[b];
        gb[b] = c ? atomicAdd(&bucketCur[b], c) : 0;
        lc[b] = 0;
    }
    __syncthreads();
    for (int i = threadIdx.x; i < n; i += BLK) {
        int c = col[e0 + i];
        int r = row[e0 + i];
        int b = c >> BSHIFT;
        int pos = gb[b] + atomicAdd(&lc[b], 1);
        staging[pos] = make_int2(r, c);
    }
}

// one block per bucket: count per node -> scan -> rowptr/dinv -> place src
// into final CSR (writes land in one ~16KB CU-local window). Fused: scale
// embA rows of this bucket by dinv (prepares z0).
__global__ void k_bucket(const int2* __restrict__ staging, const int* __restrict__ bucketPtr,
                         int* __restrict__ edges, int* __restrict__ rowptr,
                         float* __restrict__ dinv, float* __restrict__ embA, long N) {
    __shared__ int cnt[BNODES];
    __shared__ int cur[BNODES];
    __shared__ float dnv[BNODES];
    __shared__ int lds[BLK];
    const int b = blockIdx.x;
    const long lo = (long)b << BSHIFT;
    const int R = (int)(((N - lo) < BNODES) ? (N - lo) : BNODES);
    const int beg = bucketPtr[b];
    const int end = bucketPtr[b + 1];
    const int t = threadIdx.x;

    for (int i = t; i < BNODES; i += BLK) cnt[i] = 0;
    __syncthreads();
    for (int e = beg + t; e < end; e += BLK)
        atomicAdd(&cnt[staging[e].y - (int)lo], 1);
    __syncthreads();

    int v0 = cnt[2 * t];
    int v1 = cnt[2 * t + 1];
    lds[t] = v0 + v1;
    __syncthreads();
    for (int off = 1; off < BLK; off <<= 1) {
        int mine = lds[t];
        int add = (t >= off) ? lds[t - off] : 0;
        __syncthreads();
        lds[t] = mine + add;
        __syncthreads();
    }
    int excl = (t > 0) ? lds[t - 1] : 0;
    int e0 = beg + excl;
    int e1 = e0 + v0;
    cur[2 * t] = e0;
    cur[2 * t + 1] = e1;
    dnv[2 * t] = (v0 > 0) ? rsqrtf((float)v0) : 0.0f;
    dnv[2 * t + 1] = (v1 > 0) ? rsqrtf((float)v1) : 0.0f;
    if (2 * t < R) {
        rowptr[lo + 2 * t] = e0;
        dinv[lo + 2 * t] = dnv[2 * t];
    }
    if (2 * t + 1 < R) {
        rowptr[lo + 2 * t + 1] = e1;
        dinv[lo + 2 * t + 1] = dnv[2 * t + 1];
    }
    __syncthreads();

    for (int e = beg + t; e < end; e += BLK) {
        int2 p = staging[e];
        int pos = atomicAdd(&cur[p.y - (int)lo], 1);
        edges[pos] = p.x;
    }

    // fused scale: embA rows [lo, lo+R) *= dinv (z0 = dinv .* emb0)
    for (int i = t; i < R * 16; i += BLK) {
        int nloc = i >> 4;
        int q = i & 15;
        float d = dnv[nloc];
        float4* p = (float4*)(embA + (lo + nloc) * DIMH + q * 4);
        float4 v = *p;
        v.x *= d; v.y *= d; v.z *= d; v.w *= d;
        *p = v;
    }
}

// gather: 16 lanes per dst node; each lane owns a float4 slice of the 64-dim
// row. s = sum over in-edges of z[src]; then
//   emb_next = dinv[dst]*s;  acc += emb_next/25;  z_next = dinv[dst]*emb_next.
// Grid-stride over N*16 virtual threads; inner edge loop unrolled x4 for MLP.
__global__ void __launch_bounds__(BLK)
k_gather(const float* __restrict__ cur, float* __restrict__ nxt,
         float* __restrict__ acc, const float* __restrict__ dinv,
         const int* __restrict__ rowptr, const int* __restrict__ edges,
         long N, int storeNxt) {
    const long gtotal = N * 16;
    const long gstride = (long)gridDim.x * BLK;
    for (long g = (long)blockIdx.x * BLK + threadIdx.x; g < gtotal; g += gstride) {
        long node = g >> 4;
        int q = (int)(g & 15);

        int beg = rowptr[node];
        int end = rowptr[node + 1];

        float sx = 0.f, sy = 0.f, sz = 0.f, sw = 0.f;
        float tx = 0.f, ty = 0.f, tz = 0.f, tw = 0.f;
        for (int base = beg; base < end; base += 16) {
            int me = base + q;
            int psrc = (me < end) ? edges[me] : 0;
            int n = end - base;
            if (n > 16) n = 16;
            int j = 0;
            for (; j + 4 <= n; j += 4) {
                int a0 = __shfl(psrc, j + 0, 16);
                int a1 = __shfl(psrc, j + 1, 16);
                int a2 = __shfl(psrc, j + 2, 16);
                int a3 = __shfl(psrc, j + 3, 16);
                float4 v0 = *(const float4*)(cur + (long)a0 * DIMH + q * 4);
                float4 v1 = *(const float4*)(cur + (long)a1 * DIMH + q * 4);
                float4 v2 = *(const float4*)(cur + (long)a2 * DIMH + q * 4);
                float4 v3 = *(const float4*)(cur + (long)a3 * DIMH + q * 4);
                sx += v0.x; sy += v0.y; sz += v0.z; sw += v0.w;
                tx += v1.x; ty += v1.y; tz += v1.z; tw += v1.w;
                sx += v2.x; sy += v2.y; sz += v2.z; sw += v2.w;
                tx += v3.x; ty += v3.y; tz += v3.z; tw += v3.w;
            }
            for (; j < n; ++j) {
                int a = __shfl(psrc, j, 16);
                float4 v = *(const float4*)(cur + (long)a * DIMH + q * 4);
                sx += v.x; sy += v.y; sz += v.z; sw += v.w;
            }
        }
        sx += tx; sy += ty; sz += tz; sw += tw;

        float d = dinv[node];
        float ex = d * sx, ey = d * sy, ez = d * sz, ew = d * sw;

        long off = node * DIMH + q * 4;
        const float sc = 1.0f / 25.0f;
        float4 a = *(const float4*)(acc + off);
        a.x += ex * sc; a.y += ey * sc; a.z += ez * sc; a.w += ew * sc;
        *(float4*)(acc + off) = a;
        if (storeNxt)
            *(float4*)(nxt + off) = make_float4(d * ex, d * ey, d * ez, d * ew);
    }
}

// ---------------------------------------------------------------------------
extern "C" void kernel_launch(void* const* d_in, const int* in_sizes, int n_in,
                              void* d_out, int out_size, void* d_ws, size_t ws_size,
                              hipStream_t stream) {
    const float* uemb = (const float*)d_in[0];
    const float* iemb = (const float*)d_in[1];
    const int*   edge = (const int*)d_in[2];

    const long uElems = in_sizes[0];          // 100000*64
    const long iElems = in_sizes[1];          // 50000*64
    const long E      = in_sizes[2] / 2;      // 1200000
    const long total  = uElems + iElems;      // N*64
    const long N      = total / DIMH;         // 150000

    const int* row = edge;      // edge_index[0] = src
    const int* col = edge + E;  // edge_index[1] = dst

    float* acc = (float*)d_out;

    const int NB = (int)((N + BNODES - 1) >> BSHIFT);   // 293 buckets

    // workspace layout (all bases 256B-aligned: pads are multiples of 64 ints)
    const long Npad = (N + 63) & ~63L;
    const long Epad = (E + 63) & ~63L;
    int*   rowptr    = (int*)d_ws;                 // N+1 ints
    float* dinv      = (float*)(rowptr + Npad + 64);
    int*   edges     = (int*)(dinv + Npad);        // E src indices (CSR order)
    int*   bucketCnt = edges + Epad;               // 1024
    int*   bucketPtr = bucketCnt + 1024;           // 1024 (NB+1 used)
    int*   bucketCur = bucketPtr + 1024;           // 1024
    float* embA      = (float*)(bucketCur + 1024); // N*64 floats (z ping)
    float* embB      = embA + total;               // N*64 floats (z pong)
    int2*  staging   = (int2*)embB;                // E pairs; dead before gather0

    const long total4 = total / 4;
    const int gInit = (int)((total4 + BLK - 1) / BLK);
    k_init<<<gInit, BLK, 0, stream>>>(uemb, iemb, embA, acc, bucketCnt, uElems, total);
    k_binhist<<<512, BLK, 0, stream>>>(col, bucketCnt, E);
    k_binscan<<<1, BLK, 0, stream>>>(bucketCnt, bucketPtr, bucketCur, NB, (int)E,
                                     rowptr + N);
    k_binscatter<<<(int)((E + EB - 1) / EB), BLK, 0, stream>>>(row, col, bucketCur,
                                                               staging, E);
    k_bucket<<<NB, BLK, 0, stream>>>(staging, bucketPtr, edges, rowptr, dinv, embA, N);

    float* cur = embA;
    float* nxt = embB;
    for (int l = 0; l < 4; ++l) {
        k_gather<<<2048, BLK, 0, stream>>>(cur, nxt, acc, dinv, rowptr, edges, N,
                                           (l < 3) ? 1 : 0);
        float* t = cur; cur = nxt; nxt = t;
    }
}

// Round 7
// 307.658 us; speedup vs baseline: 1.5724x; 1.3123x over previous
//
#include <hip/hip_runtime.h>

// LightGCN propagation on MI355X — CSR-gather, separable-norm, binned CSR
// build, fp16 propagated state.
// N = 150000 nodes, D = 64, E = 1.2M edges, 4 layers.
// norm = dinv[src]*dinv[dst] is factored: keep z = dinv .* emb in FP16
// (halves the random-gather granule: 128 B/row); all accumulation fp32.
// CSR build: bucket edges by dst>>9, then one block per bucket — CU-local
// writes (round-6 win: k_fill 95us -> build path out of top-5).
// d_out (= acc, fp32) accumulates layer embeddings pre-scaled by 1/25.

#define DIMH 64
#define BLK 256
#define BSHIFT 9                    // 512 nodes per bucket
#define BNODES 512
#define EB 8192                     // edges per binscatter block

typedef float    f4  __attribute__((ext_vector_type(4)));
typedef _Float16 h4  __attribute__((ext_vector_type(4)));

// ---------------------------------------------------------------------------
// init: embA(h16) = concat(user, item); acc = embA/25; bucketCnt = 0 (fused).
__global__ void k_init(const float* __restrict__ uemb, const float* __restrict__ iemb,
                       _Float16* __restrict__ embA, float* __restrict__ acc,
                       int* __restrict__ bucketCnt, long uElems, long totalElems) {
    long t = (long)blockIdx.x * BLK + threadIdx.x;
    if (t < 1024) bucketCnt[t] = 0;
    long base = t * 4;
    if (base >= totalElems) return;
    f4 v = (base < uElems) ? *(const f4*)(uemb + base)
                           : *(const f4*)(iemb + (base - uElems));
    *(h4*)(embA + base) = __builtin_convertvector(v, h4);
    *(f4*)(acc + base) = v * (1.0f / 25.0f);
}

// bucket histogram over dst (LDS pre-aggregation, few global atomics).
__global__ void k_binhist(const int* __restrict__ col, int* __restrict__ bucketCnt,
                          long E) {
    __shared__ int h[BNODES];
    for (int i = threadIdx.x; i < BNODES; i += BLK) h[i] = 0;
    __syncthreads();
    const long stride = (long)gridDim.x * BLK;
    for (long e = (long)blockIdx.x * BLK + threadIdx.x; e < E; e += stride)
        atomicAdd(&h[col[e] >> BSHIFT], 1);
    __syncthreads();
    for (int i = threadIdx.x; i < BNODES; i += BLK)
        if (h[i]) atomicAdd(&bucketCnt[i], h[i]);
}

// single-block exclusive scan of bucketCnt[NB] -> bucketPtr, bucketCur.
// Also bucketPtr[NB] = E, rowptr[N] = E.
__global__ void k_binscan(const int* __restrict__ bucketCnt, int* __restrict__ bucketPtr,
                          int* __restrict__ bucketCur, int NB, int E,
                          int* __restrict__ rowptrN) {
    __shared__ int lds[BLK];
    int t = threadIdx.x;
    int v0 = (2 * t < NB) ? bucketCnt[2 * t] : 0;
    int v1 = (2 * t + 1 < NB) ? bucketCnt[2 * t + 1] : 0;
    lds[t] = v0 + v1;
    __syncthreads();
    for (int off = 1; off < BLK; off <<= 1) {
        int mine = lds[t];
        int add = (t >= off) ? lds[t - off] : 0;
        __syncthreads();
        lds[t] = mine + add;
        __syncthreads();
    }
    int excl = (t > 0) ? lds[t - 1] : 0;
    if (2 * t < NB)     { bucketPtr[2 * t] = excl;          bucketCur[2 * t] = excl; }
    if (2 * t + 1 < NB) { bucketPtr[2 * t + 1] = excl + v0; bucketCur[2 * t + 1] = excl + v0; }
    if (t == 0) { bucketPtr[NB] = E; *rowptrN = E; }
}

// scatter (src,dst) pairs into bucket-grouped staging. Per-block LDS
// histogram -> one global reservation per (block,bucket) -> writes to each
// bucket are a contiguous ~16-edge run from a single CU (line-local).
__global__ void k_binscatter(const int* __restrict__ row, const int* __restrict__ col,
                             int* __restrict__ bucketCur, int2* __restrict__ staging,
                             long E) {
    __shared__ int h[BNODES];
    __shared__ int gb[BNODES];
    __shared__ int lc[BNODES];
    const long e0 = (long)blockIdx.x * EB;
    const int n = (int)((E - e0 < EB) ? (E - e0) : EB);
    for (int i = threadIdx.x; i < BNODES; i += BLK) h[i] = 0;
    __syncthreads();
    for (int i = threadIdx.x; i < n; i += BLK)
        atomicAdd(&h[col[e0 + i] >> BSHIFT], 1);
    __syncthreads();
    for (int b = threadIdx.x; b < BNODES; b += BLK) {
        int c = h[b];
        gb[b] = c ? atomicAdd(&bucketCur[b], c) : 0;
        lc[b] = 0;
    }
    __syncthreads();
    for (int i = threadIdx.x; i < n; i += BLK) {
        int c = col[e0 + i];
        int r = row[e0 + i];
        int b = c >> BSHIFT;
        int pos = gb[b] + atomicAdd(&lc[b], 1);
        staging[pos] = make_int2(r, c);
    }
}

// one block per bucket: count per node -> scan -> rowptr/dinv -> place src
// into final CSR (writes land in one ~16KB CU-local window). Fused: scale
// embA rows of this bucket by dinv (prepares z0 = dinv .* emb0, fp16).
__global__ void k_bucket(const int2* __restrict__ staging, const int* __restrict__ bucketPtr,
                         int* __restrict__ edges, int* __restrict__ rowptr,
                         float* __restrict__ dinv, _Float16* __restrict__ embA, long N) {
    __shared__ int cnt[BNODES];
    __shared__ int cur[BNODES];
    __shared__ float dnv[BNODES];
    __shared__ int lds[BLK];
    const int b = blockIdx.x;
    const long lo = (long)b << BSHIFT;
    const int R = (int)(((N - lo) < BNODES) ? (N - lo) : BNODES);
    const int beg = bucketPtr[b];
    const int end = bucketPtr[b + 1];
    const int t = threadIdx.x;

    for (int i = t; i < BNODES; i += BLK) cnt[i] = 0;
    __syncthreads();
    for (int e = beg + t; e < end; e += BLK)
        atomicAdd(&cnt[staging[e].y - (int)lo], 1);
    __syncthreads();

    int v0 = cnt[2 * t];
    int v1 = cnt[2 * t + 1];
    lds[t] = v0 + v1;
    __syncthreads();
    for (int off = 1; off < BLK; off <<= 1) {
        int mine = lds[t];
        int add = (t >= off) ? lds[t - off] : 0;
        __syncthreads();
        lds[t] = mine + add;
        __syncthreads();
    }
    int excl = (t > 0) ? lds[t - 1] : 0;
    int e0 = beg + excl;
    int e1 = e0 + v0;
    cur[2 * t] = e0;
    cur[2 * t + 1] = e1;
    dnv[2 * t] = (v0 > 0) ? rsqrtf((float)v0) : 0.0f;
    dnv[2 * t + 1] = (v1 > 0) ? rsqrtf((float)v1) : 0.0f;
    if (2 * t < R) {
        rowptr[lo + 2 * t] = e0;
        dinv[lo + 2 * t] = dnv[2 * t];
    }
    if (2 * t + 1 < R) {
        rowptr[lo + 2 * t + 1] = e1;
        dinv[lo + 2 * t + 1] = dnv[2 * t + 1];
    }
    __syncthreads();

    for (int e = beg + t; e < end; e += BLK) {
        int2 p = staging[e];
        int pos = atomicAdd(&cur[p.y - (int)lo], 1);
        edges[pos] = p.x;
    }

    // fused scale: embA rows [lo, lo+R) *= dinv (z0 = dinv .* emb0), fp16.
    for (int i = t; i < R * 16; i += BLK) {
        int nloc = i >> 4;
        int q = i & 15;
        float d = dnv[nloc];
        h4* p = (h4*)(embA + (lo + nloc) * DIMH) + q;
        f4 v = __builtin_convertvector(*p, f4);
        *p = __builtin_convertvector(v * d, h4);
    }
}

// gather: 16 lanes per dst node; each lane owns 4 dims (8 B fp16 slice).
// s(fp32) = sum over in-edges of z[src]; then
//   emb_next = dinv[dst]*s;  acc += emb_next/25 (fp32);
//   z_next = fp16(dinv[dst]*emb_next).
// Inner edge loop unrolled x4 for MLP (4 independent 128 B row loads).
__global__ void __launch_bounds__(BLK)
k_gather(const _Float16* __restrict__ cur, _Float16* __restrict__ nxt,
         float* __restrict__ acc, const float* __restrict__ dinv,
         const int* __restrict__ rowptr, const int* __restrict__ edges,
         long N, int storeNxt) {
    long g = (long)blockIdx.x * BLK + threadIdx.x;
    if (g >= N * 16) return;
    long node = g >> 4;
    int q = (int)(g & 15);

    int beg = rowptr[node];
    int end = rowptr[node + 1];

    f4 s = {0.f, 0.f, 0.f, 0.f};
    f4 t2 = {0.f, 0.f, 0.f, 0.f};
    for (int base = beg; base < end; base += 16) {
        int me = base + q;
        int psrc = (me < end) ? edges[me] : 0;
        int n = end - base;
        if (n > 16) n = 16;
        int j = 0;
        for (; j + 4 <= n; j += 4) {
            int a0 = __shfl(psrc, j + 0, 16);
            int a1 = __shfl(psrc, j + 1, 16);
            int a2 = __shfl(psrc, j + 2, 16);
            int a3 = __shfl(psrc, j + 3, 16);
            h4 v0 = ((const h4*)(cur + (long)a0 * DIMH))[q];
            h4 v1 = ((const h4*)(cur + (long)a1 * DIMH))[q];
            h4 v2 = ((const h4*)(cur + (long)a2 * DIMH))[q];
            h4 v3 = ((const h4*)(cur + (long)a3 * DIMH))[q];
            s  += __builtin_convertvector(v0, f4);
            t2 += __builtin_convertvector(v1, f4);
            s  += __builtin_convertvector(v2, f4);
            t2 += __builtin_convertvector(v3, f4);
        }
        for (; j < n; ++j) {
            int a = __shfl(psrc, j, 16);
            h4 v = ((const h4*)(cur + (long)a * DIMH))[q];
            s += __builtin_convertvector(v, f4);
        }
    }
    s += t2;

    float d = dinv[node];
    f4 e = s * d;

    long off = node * DIMH + q * 4;
    f4 a = *(const f4*)(acc + off);
    *(f4*)(acc + off) = a + e * (1.0f / 25.0f);
    if (storeNxt)
        *(h4*)(nxt + off) = __builtin_convertvector(e * d, h4);
}

// ---------------------------------------------------------------------------
extern "C" void kernel_launch(void* const* d_in, const int* in_sizes, int n_in,
                              void* d_out, int out_size, void* d_ws, size_t ws_size,
                              hipStream_t stream) {
    const float* uemb = (const float*)d_in[0];
    const float* iemb = (const float*)d_in[1];
    const int*   edge = (const int*)d_in[2];

    const long uElems = in_sizes[0];          // 100000*64
    const long iElems = in_sizes[1];          // 50000*64
    const long E      = in_sizes[2] / 2;      // 1200000
    const long total  = uElems + iElems;      // N*64
    const long N      = total / DIMH;         // 150000

    const int* row = edge;      // edge_index[0] = src
    const int* col = edge + E;  // edge_index[1] = dst

    float* acc = (float*)d_out;

    const int NB = (int)((N + BNODES - 1) >> BSHIFT);   // 293 buckets

    // workspace layout (all bases 256B-aligned: pads are multiples of 64 ints)
    const long Npad = (N + 63) & ~63L;
    const long Epad = (E + 63) & ~63L;
    int*      rowptr    = (int*)d_ws;                 // N+1 ints
    float*    dinv      = (float*)(rowptr + Npad + 64);
    int*      edges     = (int*)(dinv + Npad);        // E src indices (CSR order)
    int*      bucketCnt = edges + Epad;               // 1024
    int*      bucketPtr = bucketCnt + 1024;           // 1024 (NB+1 used)
    int*      bucketCur = bucketPtr + 1024;           // 1024
    _Float16* embA      = (_Float16*)(bucketCur + 1024); // N*64 fp16 (z ping)
    _Float16* embB      = embA + total;               // N*64 fp16 (z pong)
    int2*     staging   = (int2*)embB;                // E pairs; dead before gather0

    const long total4 = total / 4;
    const int gInit = (int)((total4 + BLK - 1) / BLK);
    k_init<<<gInit, BLK, 0, stream>>>(uemb, iemb, embA, acc, bucketCnt, uElems, total);
    k_binhist<<<512, BLK, 0, stream>>>(col, bucketCnt, E);
    k_binscan<<<1, BLK, 0, stream>>>(bucketCnt, bucketPtr, bucketCur, NB, (int)E,
                                     rowptr + N);
    k_binscatter<<<(int)((E + EB - 1) / EB), BLK, 0, stream>>>(row, col, bucketCur,
                                                               staging, E);
    k_bucket<<<NB, BLK, 0, stream>>>(staging, bucketPtr, edges, rowptr, dinv, embA, N);

    _Float16* cur = embA;
    _Float16* nxt = embB;
    const int gGather = (int)((N * 16 + BLK - 1) / BLK);
    for (int l = 0; l < 4; ++l) {
        k_gather<<<gGather, BLK, 0, stream>>>(cur, nxt, acc, dinv, rowptr, edges, N,
                                              (l < 3) ? 1 : 0);
        _Float16* t = cur; cur = nxt; nxt = t;
    }
}

// Round 8
// 294.864 us; speedup vs baseline: 1.6406x; 1.0434x over previous
//
#include <hip/hip_runtime.h>

// LightGCN propagation on MI355X — CSR-gather, separable-norm, binned CSR
// build, fp16 propagated state, DEFERRED accumulation.
// N = 150000 nodes, D = 64, E = 1.2M edges, 4 layers.
// z = dinv .* emb (fp16). Gather layers write ONLY z_l (no acc RMW in the
// hot loop); final pass: acc += (z1+z2+z3+z4) * sqrtdeg/25, since
// emb_l = z_l * sqrt(deg) (and 0 for deg-0 nodes, matching reference).
// d_out (= acc, fp32) = sum of layer embeddings pre-scaled by 1/25.

#define DIMH 64
#define BLK 256
#define BSHIFT 9                    // 512 nodes per bucket
#define BNODES 512
#define EB 8192                     // edges per binscatter block

typedef float    f4  __attribute__((ext_vector_type(4)));
typedef _Float16 h4  __attribute__((ext_vector_type(4)));

// ---------------------------------------------------------------------------
// init: embA(h16) = concat(user, item); acc = embA/25; bucketCnt = 0 (fused).
__global__ void k_init(const float* __restrict__ uemb, const float* __restrict__ iemb,
                       _Float16* __restrict__ embA, float* __restrict__ acc,
                       int* __restrict__ bucketCnt, long uElems, long totalElems) {
    long t = (long)blockIdx.x * BLK + threadIdx.x;
    if (t < 1024) bucketCnt[t] = 0;
    long base = t * 4;
    if (base >= totalElems) return;
    f4 v = (base < uElems) ? *(const f4*)(uemb + base)
                           : *(const f4*)(iemb + (base - uElems));
    *(h4*)(embA + base) = __builtin_convertvector(v, h4);
    *(f4*)(acc + base) = v * (1.0f / 25.0f);
}

// bucket histogram over dst (LDS pre-aggregation, few global atomics).
__global__ void k_binhist(const int* __restrict__ col, int* __restrict__ bucketCnt,
                          long E) {
    __shared__ int h[BNODES];
    for (int i = threadIdx.x; i < BNODES; i += BLK) h[i] = 0;
    __syncthreads();
    const long stride = (long)gridDim.x * BLK;
    for (long e = (long)blockIdx.x * BLK + threadIdx.x; e < E; e += stride)
        atomicAdd(&h[col[e] >> BSHIFT], 1);
    __syncthreads();
    for (int i = threadIdx.x; i < BNODES; i += BLK)
        if (h[i]) atomicAdd(&bucketCnt[i], h[i]);
}

// single-block exclusive scan of bucketCnt[NB] -> bucketPtr, bucketCur.
// Also bucketPtr[NB] = E, rowptr[N] = E.
__global__ void k_binscan(const int* __restrict__ bucketCnt, int* __restrict__ bucketPtr,
                          int* __restrict__ bucketCur, int NB, int E,
                          int* __restrict__ rowptrN) {
    __shared__ int lds[BLK];
    int t = threadIdx.x;
    int v0 = (2 * t < NB) ? bucketCnt[2 * t] : 0;
    int v1 = (2 * t + 1 < NB) ? bucketCnt[2 * t + 1] : 0;
    lds[t] = v0 + v1;
    __syncthreads();
    for (int off = 1; off < BLK; off <<= 1) {
        int mine = lds[t];
        int add = (t >= off) ? lds[t - off] : 0;
        __syncthreads();
        lds[t] = mine + add;
        __syncthreads();
    }
    int excl = (t > 0) ? lds[t - 1] : 0;
    if (2 * t < NB)     { bucketPtr[2 * t] = excl;          bucketCur[2 * t] = excl; }
    if (2 * t + 1 < NB) { bucketPtr[2 * t + 1] = excl + v0; bucketCur[2 * t + 1] = excl + v0; }
    if (t == 0) { bucketPtr[NB] = E; *rowptrN = E; }
}

// scatter (src,dst) pairs into bucket-grouped staging. Per-block LDS
// histogram -> one global reservation per (block,bucket) -> writes to each
// bucket are a contiguous ~16-edge run from a single CU (line-local).
__global__ void k_binscatter(const int* __restrict__ row, const int* __restrict__ col,
                             int* __restrict__ bucketCur, int2* __restrict__ staging,
                             long E) {
    __shared__ int h[BNODES];
    __shared__ int gb[BNODES];
    __shared__ int lc[BNODES];
    const long e0 = (long)blockIdx.x * EB;
    const int n = (int)((E - e0 < EB) ? (E - e0) : EB);
    for (int i = threadIdx.x; i < BNODES; i += BLK) h[i] = 0;
    __syncthreads();
    for (int i = threadIdx.x; i < n; i += BLK)
        atomicAdd(&h[col[e0 + i] >> BSHIFT], 1);
    __syncthreads();
    for (int b = threadIdx.x; b < BNODES; b += BLK) {
        int c = h[b];
        gb[b] = c ? atomicAdd(&bucketCur[b], c) : 0;
        lc[b] = 0;
    }
    __syncthreads();
    for (int i = threadIdx.x; i < n; i += BLK) {
        int c = col[e0 + i];
        int r = row[e0 + i];
        int b = c >> BSHIFT;
        int pos = gb[b] + atomicAdd(&lc[b], 1);
        staging[pos] = make_int2(r, c);
    }
}

// one block per bucket: count per node -> scan -> rowptr/dinv -> place src
// into final CSR (writes land in one ~16KB CU-local window). Fused: scale
// embA rows of this bucket by dinv (prepares z0 = dinv .* emb0, fp16).
__global__ void k_bucket(const int2* __restrict__ staging, const int* __restrict__ bucketPtr,
                         int* __restrict__ edges, int* __restrict__ rowptr,
                         float* __restrict__ dinv, _Float16* __restrict__ embA, long N) {
    __shared__ int cnt[BNODES];
    __shared__ int cur[BNODES];
    __shared__ float dnv[BNODES];
    __shared__ int lds[BLK];
    const int b = blockIdx.x;
    const long lo = (long)b << BSHIFT;
    const int R = (int)(((N - lo) < BNODES) ? (N - lo) : BNODES);
    const int beg = bucketPtr[b];
    const int end = bucketPtr[b + 1];
    const int t = threadIdx.x;

    for (int i = t; i < BNODES; i += BLK) cnt[i] = 0;
    __syncthreads();
    for (int e = beg + t; e < end; e += BLK)
        atomicAdd(&cnt[staging[e].y - (int)lo], 1);
    __syncthreads();

    int v0 = cnt[2 * t];
    int v1 = cnt[2 * t + 1];
    lds[t] = v0 + v1;
    __syncthreads();
    for (int off = 1; off < BLK; off <<= 1) {
        int mine = lds[t];
        int add = (t >= off) ? lds[t - off] : 0;
        __syncthreads();
        lds[t] = mine + add;
        __syncthreads();
    }
    int excl = (t > 0) ? lds[t - 1] : 0;
    int e0 = beg + excl;
    int e1 = e0 + v0;
    cur[2 * t] = e0;
    cur[2 * t + 1] = e1;
    dnv[2 * t] = (v0 > 0) ? rsqrtf((float)v0) : 0.0f;
    dnv[2 * t + 1] = (v1 > 0) ? rsqrtf((float)v1) : 0.0f;
    if (2 * t < R) {
        rowptr[lo + 2 * t] = e0;
        dinv[lo + 2 * t] = dnv[2 * t];
    }
    if (2 * t + 1 < R) {
        rowptr[lo + 2 * t + 1] = e1;
        dinv[lo + 2 * t + 1] = dnv[2 * t + 1];
    }
    __syncthreads();

    for (int e = beg + t; e < end; e += BLK) {
        int2 p = staging[e];
        int pos = atomicAdd(&cur[p.y - (int)lo], 1);
        edges[pos] = p.x;
    }

    // fused scale: embA rows [lo, lo+R) *= dinv (z0 = dinv .* emb0), fp16.
    for (int i = t; i < R * 16; i += BLK) {
        int nloc = i >> 4;
        int q = i & 15;
        float d = dnv[nloc];
        h4* p = (h4*)(embA + (lo + nloc) * DIMH) + q;
        f4 v = __builtin_convertvector(*p, f4);
        *p = __builtin_convertvector(v * d, h4);
    }
}

// gather: 16 lanes per dst node; each lane owns 4 dims (8 B fp16 slice).
// s(fp32) = sum over in-edges of z[src];  z_next = fp16(dinv[dst]^2 * s).
// NO acc traffic here (deferred to k_final).
__global__ void __launch_bounds__(BLK)
k_gather(const _Float16* __restrict__ cur, _Float16* __restrict__ nxt,
         const float* __restrict__ dinv,
         const int* __restrict__ rowptr, const int* __restrict__ edges, long N) {
    long g = (long)blockIdx.x * BLK + threadIdx.x;
    if (g >= N * 16) return;
    long node = g >> 4;
    int q = (int)(g & 15);

    int beg = rowptr[node];
    int end = rowptr[node + 1];

    f4 s = {0.f, 0.f, 0.f, 0.f};
    f4 t2 = {0.f, 0.f, 0.f, 0.f};
    for (int base = beg; base < end; base += 16) {
        int me = base + q;
        int psrc = (me < end) ? edges[me] : 0;
        int n = end - base;
        if (n > 16) n = 16;
        int j = 0;
        for (; j + 4 <= n; j += 4) {
            int a0 = __shfl(psrc, j + 0, 16);
            int a1 = __shfl(psrc, j + 1, 16);
            int a2 = __shfl(psrc, j + 2, 16);
            int a3 = __shfl(psrc, j + 3, 16);
            h4 v0 = ((const h4*)(cur + (long)a0 * DIMH))[q];
            h4 v1 = ((const h4*)(cur + (long)a1 * DIMH))[q];
            h4 v2 = ((const h4*)(cur + (long)a2 * DIMH))[q];
            h4 v3 = ((const h4*)(cur + (long)a3 * DIMH))[q];
            s  += __builtin_convertvector(v0, f4);
            t2 += __builtin_convertvector(v1, f4);
            s  += __builtin_convertvector(v2, f4);
            t2 += __builtin_convertvector(v3, f4);
        }
        for (; j < n; ++j) {
            int a = __shfl(psrc, j, 16);
            h4 v = ((const h4*)(cur + (long)a * DIMH))[q];
            s += __builtin_convertvector(v, f4);
        }
    }
    s += t2;

    float d = dinv[node];
    ((h4*)(nxt + node * DIMH))[q] = __builtin_convertvector(s * (d * d), h4);
}

// final: acc += (z1+z2+z3+z4) * (sqrtdeg/25).  emb_l = z_l*sqrt(deg);
// deg-0 nodes get factor 0 (their emb_l are all 0), matching reference.
__global__ void __launch_bounds__(BLK)
k_final(const _Float16* __restrict__ z1, const _Float16* __restrict__ z2,
        const _Float16* __restrict__ z3, const _Float16* __restrict__ z4,
        const float* __restrict__ dinv, float* __restrict__ acc, long N) {
    long g = (long)blockIdx.x * BLK + threadIdx.x;
    if (g >= N * 16) return;
    long node = g >> 4;
    int q = (int)(g & 15);
    float d = dinv[node];
    float f = (d > 0.f) ? (1.0f / d) * (1.0f / 25.0f) : 0.f;
    long off = node * DIMH + q * 4;
    f4 zs = __builtin_convertvector(*(const h4*)(z1 + off), f4)
          + __builtin_convertvector(*(const h4*)(z2 + off), f4)
          + __builtin_convertvector(*(const h4*)(z3 + off), f4)
          + __builtin_convertvector(*(const h4*)(z4 + off), f4);
    f4 a = *(const f4*)(acc + off);
    *(f4*)(acc + off) = a + zs * f;
}

// ---------------------------------------------------------------------------
extern "C" void kernel_launch(void* const* d_in, const int* in_sizes, int n_in,
                              void* d_out, int out_size, void* d_ws, size_t ws_size,
                              hipStream_t stream) {
    const float* uemb = (const float*)d_in[0];
    const float* iemb = (const float*)d_in[1];
    const int*   edge = (const int*)d_in[2];

    const long uElems = in_sizes[0];          // 100000*64
    const long iElems = in_sizes[1];          // 50000*64
    const long E      = in_sizes[2] / 2;      // 1200000
    const long total  = uElems + iElems;      // N*64
    const long N      = total / DIMH;         // 150000

    const int* row = edge;      // edge_index[0] = src
    const int* col = edge + E;  // edge_index[1] = dst

    float* acc = (float*)d_out;

    const int NB = (int)((N + BNODES - 1) >> BSHIFT);   // 293 buckets

    // workspace layout (all bases 256B-aligned: pads are multiples of 64 ints)
    const long Npad = (N + 63) & ~63L;
    const long Epad = (E + 63) & ~63L;
    int*      rowptr    = (int*)d_ws;                 // N+1 ints
    float*    dinv      = (float*)(rowptr + Npad + 64);
    int*      edges     = (int*)(dinv + Npad);        // E src indices (CSR order)
    int*      bucketCnt = edges + Epad;               // 1024
    int*      bucketPtr = bucketCnt + 1024;           // 1024 (NB+1 used)
    int*      bucketCur = bucketPtr + 1024;           // 1024
    _Float16* embA      = (_Float16*)(bucketCur + 1024); // z0, N*64 fp16
    _Float16* zb0       = embA + total;               // z1
    _Float16* zb1       = zb0 + total;                // z2
    _Float16* zb2       = zb1 + total;                // z3
    _Float16* zb3       = zb2 + total;                // z4
    int2*     staging   = (int2*)zb0;  // E pairs; consumed by k_bucket before
                                       // gather-0 writes zb0 (same stream)

    const long total4 = total / 4;
    const int gInit = (int)((total4 + BLK - 1) / BLK);
    k_init<<<gInit, BLK, 0, stream>>>(uemb, iemb, embA, acc, bucketCnt, uElems, total);
    k_binhist<<<512, BLK, 0, stream>>>(col, bucketCnt, E);
    k_binscan<<<1, BLK, 0, stream>>>(bucketCnt, bucketPtr, bucketCur, NB, (int)E,
                                     rowptr + N);
    k_binscatter<<<(int)((E + EB - 1) / EB), BLK, 0, stream>>>(row, col, bucketCur,
                                                               staging, E);
    k_bucket<<<NB, BLK, 0, stream>>>(staging, bucketPtr, edges, rowptr, dinv, embA, N);

    const int gGather = (int)((N * 16 + BLK - 1) / BLK);
    _Float16* zs[5] = {embA, zb0, zb1, zb2, zb3};
    for (int l = 0; l < 4; ++l)
        k_gather<<<gGather, BLK, 0, stream>>>(zs[l], zs[l + 1], dinv, rowptr, edges, N);
    k_final<<<gGather, BLK, 0, stream>>>(zb0, zb1, zb2, zb3, dinv, acc, N);
}